// Round 1
// baseline (1141.540 us; speedup 1.0000x reference)
//
#include <hip/hip_runtime.h>

// ---------------------------------------------------------------------------
// Qwen3 attention block: B=2 S=1024 H=4096 NH=32 NKV=8 D=128
// Round 0: correct baseline. bf16 MFMA GEMMs (fp32 converted at LDS staging),
// fused rmsnorm+rope, flash-style attention with online softmax.
// ---------------------------------------------------------------------------

typedef float    f32x4  __attribute__((ext_vector_type(4)));
typedef __bf16   bf16x8 __attribute__((ext_vector_type(8)));
typedef unsigned short u16x4 __attribute__((ext_vector_type(4)));

__device__ __forceinline__ unsigned short f2b(float f) {
    union { float f; unsigned int u; } x;
    x.f = f;
    unsigned int u = x.u;
    unsigned int r = u + 0x7fffu + ((u >> 16) & 1u);   // RNE
    return (unsigned short)(r >> 16);
}

// ---------------------------------------------------------------------------
// GEMM: C[M,N] = A[M,K] @ W[N,K]^T   (A,W fp32 in; bf16 MFMA; C fp32 out)
// 128x128 tile, BK=32, 256 threads = 4 waves in 2x2, each wave 64x64 via
// 4x4 grid of mfma_f32_16x16x32_bf16.
// A-frag: lane(q=lane>>4, l=lane&15) holds A[m=l][k=q*8+j]
// B-frag:                       holds W[n=l][k=q*8+j]
// C:      lane holds D[row=q*4+reg][col=l]
// ---------------------------------------------------------------------------
__global__ __launch_bounds__(256) void gemm_bt(const float* __restrict__ A,
                                               const float* __restrict__ W,
                                               float* __restrict__ C,
                                               int K, int N) {
    // pad 32 -> 40 ushorts per row: row stride 80B = 20 dwords -> 2-way banks
    __shared__ __align__(16) unsigned short As[128][40];
    __shared__ __align__(16) unsigned short Bs[128][40];

    const int tid  = threadIdx.x;
    const int bm   = blockIdx.y, bn = blockIdx.x;
    const int wave = tid >> 6,  lane = tid & 63;
    const int wm   = wave >> 1, wn   = wave & 1;
    const int quad = lane >> 4, l15  = lane & 15;

    f32x4 acc[4][4] = {};

    const int arow = bm * 128;
    const int brow = bn * 128;

    for (int k0 = 0; k0 < K; k0 += 32) {
        // stage A tile: 128 rows x 32 cols fp32 -> bf16 LDS
        #pragma unroll
        for (int i = 0; i < 4; i++) {
            int idx = tid + 256 * i;
            int r = idx >> 3, c4 = idx & 7;
            float4 v = *(const float4*)(A + (size_t)(arow + r) * K + k0 + c4 * 4);
            u16x4 hv;
            hv.x = f2b(v.x); hv.y = f2b(v.y); hv.z = f2b(v.z); hv.w = f2b(v.w);
            *(u16x4*)&As[r][c4 * 4] = hv;
        }
        #pragma unroll
        for (int i = 0; i < 4; i++) {
            int idx = tid + 256 * i;
            int r = idx >> 3, c4 = idx & 7;
            float4 v = *(const float4*)(W + (size_t)(brow + r) * K + k0 + c4 * 4);
            u16x4 hv;
            hv.x = f2b(v.x); hv.y = f2b(v.y); hv.z = f2b(v.z); hv.w = f2b(v.w);
            *(u16x4*)&Bs[r][c4 * 4] = hv;
        }
        __syncthreads();

        bf16x8 af[4], bfr[4];
        #pragma unroll
        for (int i = 0; i < 4; i++)
            af[i] = *(const bf16x8*)&As[wm * 64 + i * 16 + l15][quad * 8];
        #pragma unroll
        for (int j = 0; j < 4; j++)
            bfr[j] = *(const bf16x8*)&Bs[wn * 64 + j * 16 + l15][quad * 8];

        #pragma unroll
        for (int i = 0; i < 4; i++)
            #pragma unroll
            for (int j = 0; j < 4; j++)
                acc[i][j] = __builtin_amdgcn_mfma_f32_16x16x32_bf16(af[i], bfr[j], acc[i][j], 0, 0, 0);
        __syncthreads();
    }

    #pragma unroll
    for (int i = 0; i < 4; i++)
        #pragma unroll
        for (int j = 0; j < 4; j++)
            #pragma unroll
            for (int r = 0; r < 4; r++) {
                int row = arow + wm * 64 + i * 16 + quad * 4 + r;
                int col = brow + wn * 64 + j * 16 + l15;
                C[(size_t)row * N + col] = acc[i][j][r];
            }
}

// ---------------------------------------------------------------------------
// RMSNorm + RoPE, fp32 [rows][nh*128] -> bf16 [B][nh][S][128]
// One wave per (row, head); lane owns d=lane and d=lane+64 (the rope pair).
// ---------------------------------------------------------------------------
__global__ __launch_bounds__(256) void norm_rope(const float* __restrict__ X,
                                                 const float* __restrict__ cosp,
                                                 const float* __restrict__ sinp,
                                                 const float* __restrict__ w,
                                                 unsigned short* __restrict__ Y,
                                                 int nh) {
    const int wid  = blockIdx.x * 4 + (threadIdx.x >> 6);
    const int lane = threadIdx.x & 63;
    const int row  = wid / nh;          // 0..2047 (= b*1024+s)
    const int h    = wid - row * nh;

    const float* xp = X + (size_t)row * nh * 128 + h * 128;
    float x0 = xp[lane], x1 = xp[lane + 64];
    float ss = x0 * x0 + x1 * x1;
    #pragma unroll
    for (int off = 32; off; off >>= 1) ss += __shfl_xor(ss, off, 64);
    float r = rsqrtf(ss * (1.0f / 128.0f) + 1e-6f);
    float n0 = x0 * r * w[lane];
    float n1 = x1 * r * w[lane + 64];
    const float* cp = cosp + (size_t)row * 128;
    const float* sp = sinp + (size_t)row * 128;
    float y0 = n0 * cp[lane]      - n1 * sp[lane];
    float y1 = n1 * cp[lane + 64] + n0 * sp[lane + 64];
    const int b = row >> 10, s = row & 1023;
    unsigned short* yp = Y + (((size_t)(b * nh + h)) * 1024 + s) * 128;
    yp[lane]      = f2b(y0);
    yp[lane + 64] = f2b(y1);
}

// ---------------------------------------------------------------------------
// V transpose: fp32 [B*S][NKV*128] -> bf16 Vt[B][NKV][128][S]
// ---------------------------------------------------------------------------
__global__ __launch_bounds__(256) void v_trans(const float* __restrict__ Vf,
                                               unsigned short* __restrict__ Vt) {
    const int idx = blockIdx.x * 256 + threadIdx.x;   // over [b][h][d][s]
    const int s  = idx & 1023;
    const int d  = (idx >> 10) & 127;
    const int hb = idx >> 17;             // b*8+h
    const int b  = hb >> 3, h = hb & 7;
    float v = Vf[((size_t)(b * 1024 + s)) * 1024 + h * 128 + d];
    Vt[idx] = f2b(v);
}

// ---------------------------------------------------------------------------
// Flash attention (causal, GQA). Block = 64 Q rows = 4 waves x 16 rows.
// K-tile = 128 keys. Per wave: S(16x128) = Q(16x128)@K^T, online softmax
// (width-16 shuffle reductions; rows stay in-wave), P -> LDS (bf16, padded)
// -> A-layout frags, O += P @ V  (V pre-transposed so k is contiguous).
// ---------------------------------------------------------------------------
__global__ __launch_bounds__(256) void attn(const unsigned short* __restrict__ Qb,
                                            const unsigned short* __restrict__ Kb,
                                            const unsigned short* __restrict__ Vt,
                                            float* __restrict__ Of) {
    __shared__ __align__(16) unsigned short Plds[4][16][136]; // pad 128->136

    const int tid  = threadIdx.x;
    const int w    = tid >> 6, lane = tid & 63;
    const int quad = lane >> 4, l15 = lane & 15;
    const int qt = blockIdx.x, h = blockIdx.y, b = blockIdx.z;
    const int q0  = qt * 64;
    const int kvh = h >> 2;   // groups = 4

    const unsigned short* Qp = Qb + ((size_t)(b * 32 + h))  * 1024 * 128;
    const unsigned short* Kp = Kb + ((size_t)(b * 8 + kvh)) * 1024 * 128;
    const unsigned short* Vp = Vt + ((size_t)(b * 8 + kvh)) * 128 * 1024;

    const int qrow = q0 + w * 16 + l15;
    bf16x8 qf[4];
    #pragma unroll
    for (int ks = 0; ks < 4; ks++)
        qf[ks] = *(const bf16x8*)(Qp + (size_t)qrow * 128 + ks * 32 + quad * 8);

    float m_i[4], l_i[4];
    #pragma unroll
    for (int r = 0; r < 4; r++) { m_i[r] = -1e30f; l_i[r] = 0.0f; }
    f32x4 o[8] = {};

    const float scale = 0.08838834764831845f;  // D^-0.5
    const int ntiles = (q0 + 64 + 127) >> 7;

    for (int kt = 0; kt < ntiles; kt++) {
        f32x4 sacc[8] = {};
        #pragma unroll
        for (int ks = 0; ks < 4; ks++) {
            #pragma unroll
            for (int tn = 0; tn < 8; tn++) {
                bf16x8 kf = *(const bf16x8*)(Kp + (size_t)(kt * 128 + tn * 16 + l15) * 128 + ks * 32 + quad * 8);
                sacc[tn] = __builtin_amdgcn_mfma_f32_16x16x32_bf16(qf[ks], kf, sacc[tn], 0, 0, 0);
            }
        }

        #pragma unroll
        for (int r = 0; r < 4; r++) {
            const int qg = q0 + w * 16 + quad * 4 + r;
            float sv[8];
            float rmax = -1e30f;
            #pragma unroll
            for (int tn = 0; tn < 8; tn++) {
                float v = sacc[tn][r] * scale;
                int kg = kt * 128 + tn * 16 + l15;
                if (kg > qg) v = -1e30f;           // causal mask
                sv[tn] = v;
                rmax = fmaxf(rmax, v);
            }
            #pragma unroll
            for (int off = 8; off; off >>= 1) rmax = fmaxf(rmax, __shfl_xor(rmax, off, 16));
            float mnew  = fmaxf(m_i[r], rmax);
            float alpha = __expf(m_i[r] - mnew);
            float rsum  = 0.0f;
            #pragma unroll
            for (int tn = 0; tn < 8; tn++) {
                float p = __expf(sv[tn] - mnew);
                sv[tn] = p;
                rsum += p;
            }
            #pragma unroll
            for (int off = 8; off; off >>= 1) rsum += __shfl_xor(rsum, off, 16);
            m_i[r] = mnew;
            l_i[r] = l_i[r] * alpha + rsum;
            #pragma unroll
            for (int td = 0; td < 8; td++) o[td][r] *= alpha;
            #pragma unroll
            for (int tn = 0; tn < 8; tn++)
                Plds[w][quad * 4 + r][tn * 16 + l15] = f2b(sv[tn]);
        }

        // P @ V  (P from LDS in A-layout; V^T gives contiguous-k B-frags)
        #pragma unroll
        for (int ks = 0; ks < 4; ks++) {
            bf16x8 pf = *(const bf16x8*)&Plds[w][l15][ks * 32 + quad * 8];
            #pragma unroll
            for (int td = 0; td < 8; td++) {
                bf16x8 vf = *(const bf16x8*)(Vp + (size_t)(td * 16 + l15) * 1024 + kt * 128 + ks * 32 + quad * 8);
                o[td] = __builtin_amdgcn_mfma_f32_16x16x32_bf16(pf, vf, o[td], 0, 0, 0);
            }
        }
    }

    #pragma unroll
    for (int r = 0; r < 4; r++) {
        float inv = 1.0f / l_i[r];
        const int qg = q0 + w * 16 + quad * 4 + r;
        float* op = Of + ((size_t)(b * 1024 + qg)) * 4096 + h * 128;
        #pragma unroll
        for (int td = 0; td < 8; td++)
            op[td * 16 + l15] = o[td][r] * inv;
    }
}

// ---------------------------------------------------------------------------
extern "C" void kernel_launch(void* const* d_in, const int* in_sizes, int n_in,
                              void* d_out, int out_size, void* d_ws, size_t ws_size,
                              hipStream_t stream) {
    const float* hid  = (const float*)d_in[0];
    const float* cosp = (const float*)d_in[1];
    const float* sinp = (const float*)d_in[2];
    const float* Wq   = (const float*)d_in[3];
    const float* Wk   = (const float*)d_in[4];
    const float* Wv   = (const float*)d_in[5];
    const float* Wo   = (const float*)d_in[6];
    const float* qw   = (const float*)d_in[7];
    const float* kw   = (const float*)d_in[8];
    float* out = (float*)d_out;

    // workspace carve (fp32 + bf16 regions). Of aliases Qf (Qf dead after
    // norm_rope, which completes before attn on the same stream).
    float* Qf = (float*)d_ws;                         // 2048*4096 fp32
    float* Kf = Qf + 2048 * 4096;                     // 2048*1024 fp32
    float* Vf = Kf + 2048 * 1024;                     // 2048*1024 fp32
    unsigned short* Qb = (unsigned short*)(Vf + 2048 * 1024);  // [2][32][1024][128] bf16
    unsigned short* Kb = Qb + 2048 * 4096;                     // [2][8][1024][128] bf16
    unsigned short* Vt = Kb + 2048 * 1024;                     // [2][8][128][1024] bf16
    float* Of = Qf;                                   // reuse

    dim3 blk(256);
    // QKV projections
    gemm_bt<<<dim3(32, 16), blk, 0, stream>>>(hid, Wq, Qf, 4096, 4096);
    gemm_bt<<<dim3(8, 16),  blk, 0, stream>>>(hid, Wk, Kf, 4096, 1024);
    gemm_bt<<<dim3(8, 16),  blk, 0, stream>>>(hid, Wv, Vf, 4096, 1024);
    // norm + rope + layout
    norm_rope<<<16384, blk, 0, stream>>>(Qf, cosp, sinp, qw, Qb, 32);
    norm_rope<<<4096,  blk, 0, stream>>>(Kf, cosp, sinp, kw, Kb, 8);
    v_trans<<<8192, blk, 0, stream>>>(Vf, Vt);
    // attention
    attn<<<dim3(16, 32, 2), blk, 0, stream>>>(Qb, Kb, Vt, Of);
    // output projection
    gemm_bt<<<dim3(32, 16), blk, 0, stream>>>(Of, Wo, out, 4096, 4096);
}

// Round 2
// 554.564 us; speedup vs baseline: 2.0584x; 2.0584x over previous
//
#include <hip/hip_runtime.h>

// ---------------------------------------------------------------------------
// Qwen3 attention block: B=2 S=1024 H=4096 NH=32 NKV=8 D=128
// Round 2: bf16 pre-convert + m97-style GEMM (global_load_lds w=16, XOR
// swizzle, BK=64), balanced attention with K staged in LDS, exp2 softmax.
// ---------------------------------------------------------------------------

typedef float  f32x4  __attribute__((ext_vector_type(4)));
typedef __bf16 bf16x8 __attribute__((ext_vector_type(8)));
typedef unsigned short u16x8 __attribute__((ext_vector_type(8)));

__device__ __forceinline__ unsigned short f2b(float f) {
    union { float f; unsigned int u; } x;
    x.f = f;
    unsigned int u = x.u;
    unsigned int r = u + 0x7fffu + ((u >> 16) & 1u);   // RNE
    return (unsigned short)(r >> 16);
}

// async global->LDS, 16B per lane. LDS dst = wave-uniform base + lane*16.
__device__ __forceinline__ void async16(const unsigned short* g, unsigned short* l) {
    __builtin_amdgcn_global_load_lds(
        (const __attribute__((address_space(1))) void*)g,
        (__attribute__((address_space(3))) void*)l, 16, 0, 0);
}

// ---------------------------------------------------------------------------
// fp32 -> bf16 convert, 8 elems/thread
// ---------------------------------------------------------------------------
__global__ __launch_bounds__(256) void cvt(const float* __restrict__ s,
                                           unsigned short* __restrict__ d, int n8) {
    int i = blockIdx.x * 256 + threadIdx.x;
    if (i >= n8) return;
    const float4* s4 = (const float4*)s + (size_t)i * 2;
    float4 a = s4[0], b = s4[1];
    u16x8 o;
    o[0] = f2b(a.x); o[1] = f2b(a.y); o[2] = f2b(a.z); o[3] = f2b(a.w);
    o[4] = f2b(b.x); o[5] = f2b(b.y); o[6] = f2b(b.z); o[7] = f2b(b.w);
    *((u16x8*)d + i) = o;
}

// ---------------------------------------------------------------------------
// GEMM: C[M,N] fp32 = A[M,K]bf16 @ W[N,K]bf16^T. 128x128 tile, BK=64.
// global_load_lds(16B) staging with XOR-8 chunk swizzle:
//   LDS[r][c'] = global[r][c' ^ (r&7)]  (chunk = 16B = 8 bf16)
// Fragment read chunk (ks*4+quad) ^ (l15&7): 8 distinct bank-columns,
// 2 lanes each -> conflict-free.
// ---------------------------------------------------------------------------
__global__ __launch_bounds__(256) void gemm_bt_bf16(const unsigned short* __restrict__ A,
                                                    const unsigned short* __restrict__ W,
                                                    float* __restrict__ C,
                                                    int K, int N) {
    __shared__ __align__(16) unsigned short As[128 * 64];
    __shared__ __align__(16) unsigned short Bs[128 * 64];

    const int tid  = threadIdx.x;
    const int wave = tid >> 6, lane = tid & 63;
    const int wm   = wave >> 1, wn = wave & 1;
    const int quad = lane >> 4, l15 = lane & 15;
    const int arow = blockIdx.y * 128, brow = blockIdx.x * 128;

    // per-thread staging coordinates (chunk-linear over the 128x8-chunk tile)
    int rr[4], gc[4], slot[4];
    #pragma unroll
    for (int it = 0; it < 4; it++) {
        slot[it] = it * 4 + wave;
        int ci = slot[it] * 64 + lane;
        rr[it] = ci >> 3;
        int c  = ci & 7;
        gc[it] = c ^ (rr[it] & 7);
    }

    f32x4 acc[4][4] = {};

    for (int k0 = 0; k0 < K; k0 += 64) {
        #pragma unroll
        for (int it = 0; it < 4; it++) {
            async16(A + (size_t)(arow + rr[it]) * K + k0 + gc[it] * 8, &As[slot[it] * 512]);
            async16(W + (size_t)(brow + rr[it]) * K + k0 + gc[it] * 8, &Bs[slot[it] * 512]);
        }
        __syncthreads();

        bf16x8 af[2][4], bfr[2][4];
        #pragma unroll
        for (int ks = 0; ks < 2; ks++) {
            #pragma unroll
            for (int i = 0; i < 4; i++) {
                int rowa = wm * 64 + i * 16 + l15;
                int ch   = (ks * 4 + quad) ^ (l15 & 7);
                af[ks][i]  = *(const bf16x8*)&As[rowa * 64 + ch * 8];
                int rowb = wn * 64 + i * 16 + l15;
                bfr[ks][i] = *(const bf16x8*)&Bs[rowb * 64 + ch * 8];
            }
        }
        #pragma unroll
        for (int ks = 0; ks < 2; ks++)
            #pragma unroll
            for (int i = 0; i < 4; i++)
                #pragma unroll
                for (int j = 0; j < 4; j++)
                    acc[i][j] = __builtin_amdgcn_mfma_f32_16x16x32_bf16(af[ks][i], bfr[ks][j], acc[i][j], 0, 0, 0);
        __syncthreads();
    }

    #pragma unroll
    for (int i = 0; i < 4; i++)
        #pragma unroll
        for (int j = 0; j < 4; j++)
            #pragma unroll
            for (int r = 0; r < 4; r++) {
                int row = arow + wm * 64 + i * 16 + quad * 4 + r;
                int col = brow + wn * 64 + j * 16 + l15;
                C[(size_t)row * N + col] = acc[i][j][r];
            }
}

// ---------------------------------------------------------------------------
// RMSNorm + RoPE: fp32 [rows][rstride] (col-offset pre-applied) -> bf16
// [B][nh][S][128]. One wave per (row, head).
// ---------------------------------------------------------------------------
__global__ __launch_bounds__(256) void norm_rope(const float* __restrict__ X, int rstride,
                                                 const float* __restrict__ cosp,
                                                 const float* __restrict__ sinp,
                                                 const float* __restrict__ w,
                                                 unsigned short* __restrict__ Y, int nh) {
    const int wid  = blockIdx.x * 4 + (threadIdx.x >> 6);
    const int lane = threadIdx.x & 63;
    const int row  = wid / nh;
    const int h    = wid - row * nh;

    const float* xp = X + (size_t)row * rstride + h * 128;
    float x0 = xp[lane], x1 = xp[lane + 64];
    float ss = x0 * x0 + x1 * x1;
    #pragma unroll
    for (int off = 32; off; off >>= 1) ss += __shfl_xor(ss, off, 64);
    float r = rsqrtf(ss * (1.0f / 128.0f) + 1e-6f);
    float n0 = x0 * r * w[lane];
    float n1 = x1 * r * w[lane + 64];
    const float* cp = cosp + (size_t)row * 128;
    const float* sp = sinp + (size_t)row * 128;
    float y0 = n0 * cp[lane]      - n1 * sp[lane];
    float y1 = n1 * cp[lane + 64] + n0 * sp[lane + 64];
    const int b = row >> 10, s = row & 1023;
    unsigned short* yp = Y + (((size_t)(b * nh + h)) * 1024 + s) * 128;
    yp[lane]      = f2b(y0);
    yp[lane + 64] = f2b(y1);
}

// ---------------------------------------------------------------------------
// V transpose via LDS: fp32 V-region rows [b*1024+s][6144] (pointer
// pre-offset to col 5120) -> bf16 Vt[b][h][128][1024]. 64x64 tiles.
// grid (32,16): x = st*2+dt, y = b*8+h
// ---------------------------------------------------------------------------
__global__ __launch_bounds__(256) void v_trans(const float* __restrict__ V,
                                               unsigned short* __restrict__ Vt) {
    __shared__ float T[64][65];
    const int tid = threadIdx.x;
    const int st = blockIdx.x >> 1, dt = blockIdx.x & 1;
    const int bh = blockIdx.y, b = bh >> 3, h = bh & 7;

    const int sl = tid >> 2, c0 = (tid & 3) * 16;
    const float* src = V + (size_t)(b * 1024 + st * 64 + sl) * 6144 + h * 128 + dt * 64 + c0;
    #pragma unroll
    for (int j = 0; j < 4; j++) {
        float4 v = *(const float4*)(src + j * 4);
        *(float4*)&T[sl][c0 + j * 4] = v;
    }
    __syncthreads();

    const int dgrp = tid >> 6, sl2 = tid & 63;
    unsigned short* dst = Vt + (size_t)bh * 131072 + st * 64 + sl2;
    #pragma unroll
    for (int jd = 0; jd < 16; jd++) {
        int dl = dgrp * 16 + jd;
        dst[(size_t)(dt * 64 + dl) * 1024] = f2b(T[sl2][dl]);
    }
}

// ---------------------------------------------------------------------------
// Flash attention (causal, GQA 4:1). Block = 64 Q rows (4 waves x 16 rows),
// processes q-tiles {qt, 15-qt} -> 9 k-tiles per block (balanced).
// K-tile (128x128) staged in LDS via swizzled global_load_lds, shared by all
// waves. Softmax in exp2 domain; mask only on the single diagonal tile.
// Output bf16 [b*1024+q][4096].
// ---------------------------------------------------------------------------
__global__ __launch_bounds__(256) void attn(const unsigned short* __restrict__ Qb,
                                            const unsigned short* __restrict__ Kb,
                                            const unsigned short* __restrict__ Vt,
                                            unsigned short* __restrict__ Ob) {
    __shared__ __align__(16) unsigned short Klds[128 * 128];
    __shared__ __align__(16) unsigned short Plds[4][16][136];

    const int tid  = threadIdx.x;
    const int w    = tid >> 6, lane = tid & 63;
    const int quad = lane >> 4, l15 = lane & 15;
    const int h = blockIdx.y, b = blockIdx.z, kvh = h >> 2;

    const unsigned short* Qp = Qb + ((size_t)(b * 32 + h))   * 131072;
    const unsigned short* Kp = Kb + ((size_t)(b * 8 + kvh))  * 131072;
    const unsigned short* Vp = Vt + ((size_t)(b * 8 + kvh))  * 131072;
    const float c2 = (float)(0.08838834764831845 * 1.4426950408889634); // D^-.5 * log2(e)

    for (int half = 0; half < 2; half++) {
        const int qt = half ? (15 - (int)blockIdx.x) : (int)blockIdx.x;
        const int q0 = qt * 64;
        const int qrow = q0 + w * 16 + l15;

        bf16x8 qf[4];
        #pragma unroll
        for (int ks = 0; ks < 4; ks++)
            qf[ks] = *(const bf16x8*)(Qp + (size_t)qrow * 128 + ks * 32 + quad * 8);

        float m_i[4], l_i[4];
        #pragma unroll
        for (int r = 0; r < 4; r++) { m_i[r] = -1e30f; l_i[r] = 0.0f; }
        f32x4 o[8] = {};

        const int ntiles = (qt >> 1) + 1;
        const int nfull  = (qt * 64 + 1) >> 7;   // tiles [0,nfull) need no mask

        for (int kt = 0; kt < ntiles; kt++) {
            __syncthreads();   // Klds readers of previous tile are done
            #pragma unroll
            for (int it = 0; it < 8; it++) {
                int slot = it * 4 + w;
                int ci = slot * 64 + lane;
                int r = ci >> 4, c = ci & 15;
                int g = (c & 8) | ((c ^ r) & 7);
                async16(Kp + (size_t)(kt * 128 + r) * 128 + g * 8, &Klds[slot * 512]);
            }
            __syncthreads();

            // S = Q @ K^T
            f32x4 sacc[8] = {};
            #pragma unroll
            for (int ks = 0; ks < 4; ks++) {
                #pragma unroll
                for (int tn = 0; tn < 8; tn++) {
                    int row = tn * 16 + l15;
                    int ch  = ks * 4 + quad;
                    int chs = (ch & 8) | ((ch ^ row) & 7);
                    bf16x8 kf = *(const bf16x8*)&Klds[row * 128 + chs * 8];
                    sacc[tn] = __builtin_amdgcn_mfma_f32_16x16x32_bf16(qf[ks], kf, sacc[tn], 0, 0, 0);
                }
            }

            const bool masked = (kt >= nfull);
            #pragma unroll
            for (int r = 0; r < 4; r++) {
                float sv[8];
                float rmax = -1e30f;
                if (masked) {
                    const int qg = q0 + w * 16 + quad * 4 + r;
                    #pragma unroll
                    for (int tn = 0; tn < 8; tn++) {
                        float v = sacc[tn][r];
                        int kg = kt * 128 + tn * 16 + l15;
                        if (kg > qg) v = -1e30f;
                        sv[tn] = v;
                        rmax = fmaxf(rmax, v);
                    }
                } else {
                    #pragma unroll
                    for (int tn = 0; tn < 8; tn++) {
                        sv[tn] = sacc[tn][r];
                        rmax = fmaxf(rmax, sv[tn]);
                    }
                }
                #pragma unroll
                for (int off = 8; off; off >>= 1) rmax = fmaxf(rmax, __shfl_xor(rmax, off, 16));
                float mnew  = fmaxf(m_i[r], rmax);
                float alpha = __builtin_amdgcn_exp2f((m_i[r] - mnew) * c2);
                float rsum  = 0.0f;
                #pragma unroll
                for (int tn = 0; tn < 8; tn++) {
                    float p = __builtin_amdgcn_exp2f((sv[tn] - mnew) * c2);
                    sv[tn] = p;
                    rsum += p;
                }
                #pragma unroll
                for (int off = 8; off; off >>= 1) rsum += __shfl_xor(rsum, off, 16);
                m_i[r] = mnew;
                l_i[r] = l_i[r] * alpha + rsum;
                #pragma unroll
                for (int td = 0; td < 8; td++) o[td][r] *= alpha;
                #pragma unroll
                for (int tn = 0; tn < 8; tn++)
                    Plds[w][quad * 4 + r][tn * 16 + l15] = f2b(sv[tn]);
            }

            // O += P @ V
            #pragma unroll
            for (int ks = 0; ks < 4; ks++) {
                bf16x8 pf = *(const bf16x8*)&Plds[w][l15][ks * 32 + quad * 8];
                #pragma unroll
                for (int td = 0; td < 8; td++) {
                    bf16x8 vf = *(const bf16x8*)(Vp + (size_t)(td * 16 + l15) * 1024 + kt * 128 + ks * 32 + quad * 8);
                    o[td] = __builtin_amdgcn_mfma_f32_16x16x32_bf16(pf, vf, o[td], 0, 0, 0);
                }
            }
        }

        #pragma unroll
        for (int r = 0; r < 4; r++) {
            float inv = 1.0f / l_i[r];
            const int qg = q0 + w * 16 + quad * 4 + r;
            unsigned short* op = Ob + ((size_t)(b * 1024 + qg)) * 4096 + h * 128;
            #pragma unroll
            for (int td = 0; td < 8; td++)
                op[td * 16 + l15] = f2b(o[td][r] * inv);
        }
    }
}

// ---------------------------------------------------------------------------
extern "C" void kernel_launch(void* const* d_in, const int* in_sizes, int n_in,
                              void* d_out, int out_size, void* d_ws, size_t ws_size,
                              hipStream_t stream) {
    const float* hid  = (const float*)d_in[0];
    const float* cosp = (const float*)d_in[1];
    const float* sinp = (const float*)d_in[2];
    const float* Wq   = (const float*)d_in[3];
    const float* Wk   = (const float*)d_in[4];
    const float* Wv   = (const float*)d_in[5];
    const float* Wo   = (const float*)d_in[6];
    const float* qw   = (const float*)d_in[7];
    const float* kw   = (const float*)d_in[8];
    float* out = (float*)d_out;

    // workspace carve (~176 MB)
    char* ws = (char*)d_ws;
    float* QKVf = (float*)ws;                               // [2048][6144] fp32 (50.3MB)
    unsigned short* Ob = (unsigned short*)ws;               // alias: QKVf dead before attn
    size_t off = (size_t)2048 * 6144 * 4;
    unsigned short* hidb  = (unsigned short*)(ws + off); off += (size_t)2048 * 4096 * 2;
    unsigned short* Wqkvb = (unsigned short*)(ws + off); off += (size_t)6144 * 4096 * 2;
    unsigned short* Wob   = (unsigned short*)(ws + off); off += (size_t)4096 * 4096 * 2;
    unsigned short* Qb    = (unsigned short*)(ws + off); off += (size_t)2048 * 4096 * 2;
    unsigned short* Kb    = (unsigned short*)(ws + off); off += (size_t)2048 * 1024 * 2;
    unsigned short* Vt    = (unsigned short*)(ws + off);

    dim3 blk(256);
    // fp32 -> bf16 converts
    cvt<<<4096, blk, 0, stream>>>(hid, hidb, 1048576);
    cvt<<<8192, blk, 0, stream>>>(Wq, Wqkvb, 2097152);
    cvt<<<2048, blk, 0, stream>>>(Wk, Wqkvb + (size_t)4096 * 4096, 524288);
    cvt<<<2048, blk, 0, stream>>>(Wv, Wqkvb + (size_t)5120 * 4096, 524288);
    cvt<<<8192, blk, 0, stream>>>(Wo, Wob, 2097152);
    // fused QKV projection: [2048][6144] = hidb @ Wqkvb^T
    gemm_bt_bf16<<<dim3(48, 16), blk, 0, stream>>>(hidb, Wqkvb, QKVf, 4096, 6144);
    // norm + rope + layout
    norm_rope<<<16384, blk, 0, stream>>>(QKVf,        6144, cosp, sinp, qw, Qb, 32);
    norm_rope<<<4096,  blk, 0, stream>>>(QKVf + 4096, 6144, cosp, sinp, kw, Kb, 8);
    v_trans<<<dim3(32, 16), blk, 0, stream>>>(QKVf + 5120, Vt);
    // attention
    attn<<<dim3(8, 32, 2), blk, 0, stream>>>(Qb, Kb, Vt, Ob);
    // output projection
    gemm_bt_bf16<<<dim3(32, 16), blk, 0, stream>>>(Ob, Wob, out, 4096, 4096);
}